// Round 7
// baseline (1357.354 us; speedup 1.0000x reference)
//
#include <hip/hip_runtime.h>
#include <math.h>

// ---------------------------------------------------------------------------
// GIN, 3 layers, N=100000, E=1000000, D=64, fp32 in/out.
// Round 7: fused k_layer with EDGE-PARALLEL gather.
//  - CSR is dst-sorted -> each 64-node block owns a contiguous edge range.
//  - Gather: stage 64 x-rows into block LDS tile (coalesced, fuses "+x"),
//    then a flat edge loop (16 groups x 2 edges/iter) with ds_add_f32 LDS
//    atomics into the dst row. No per-node dependent chains.
//  - CSR entry = int4 (src, w-bits, dst, 0) so the edge loop knows dst.
//  - MFMA bf16x3 MLP unchanged. Routing: x -> buf1 -> buf2 -> d_out.
// ---------------------------------------------------------------------------

#define FEAT 64

typedef __attribute__((ext_vector_type(8))) short bfrag;   // 8 bf16 (4 VGPRs)
typedef __attribute__((ext_vector_type(4))) float ffrag;   // 4 fp32 acc

__device__ __forceinline__ unsigned short f2bf_rne(float x) {
    union { float f; unsigned u; } v; v.f = x;
    unsigned r = (v.u + 0x7fffu + ((v.u >> 16) & 1u)) >> 16;
    return (unsigned short)r;
}
__device__ __forceinline__ float bf2f(unsigned short h) {
    union { unsigned u; float f; } v; v.u = ((unsigned)h) << 16;
    return v.f;
}

// ---------------- CSR build ------------------------------------------------
__global__ void k_zero(int* p, int n) {
    int i = blockIdx.x * 256 + threadIdx.x;
    if (i < n) p[i] = 0;
}

__global__ void k_hist(const int* __restrict__ dst, int* __restrict__ deg, int E) {
    int e = blockIdx.x * 256 + threadIdx.x;
    if (e < E) atomicAdd(&deg[dst[e]], 1);
}

__global__ void k_scan1(const int* __restrict__ deg, int* __restrict__ part,
                        int* __restrict__ bsums, int n) {
    __shared__ int tmp[256];
    int tid = threadIdx.x;
    int i = blockIdx.x * 256 + tid;
    int v = (i < n) ? deg[i] : 0;
    tmp[tid] = v;
    __syncthreads();
    for (int off = 1; off < 256; off <<= 1) {
        int t = (tid >= off) ? tmp[tid - off] : 0;
        __syncthreads();
        tmp[tid] += t;
        __syncthreads();
    }
    if (i < n) part[i] = tmp[tid] - v;            // exclusive
    if (tid == 255) bsums[blockIdx.x] = tmp[255]; // block total
}

__global__ void k_scan2(int* bsums, int nb) {
    __shared__ int tmp[512];
    int tid = threadIdx.x;
    int v = (tid < nb) ? bsums[tid] : 0;
    tmp[tid] = v;
    __syncthreads();
    for (int off = 1; off < 512; off <<= 1) {
        int t = (tid >= off) ? tmp[tid - off] : 0;
        __syncthreads();
        tmp[tid] += t;
        __syncthreads();
    }
    if (tid < nb) bsums[tid] = tmp[tid] - v;
}

__global__ void k_add(int* __restrict__ rowptr, int* __restrict__ pos,
                      const int* __restrict__ bsums, int n, int E) {
    int i = blockIdx.x * 256 + threadIdx.x;
    if (i < n) {
        int v = rowptr[i] + bsums[i >> 8];
        rowptr[i] = v;
        pos[i] = v;
    } else if (i == n) {
        rowptr[n] = E;
    }
}

__global__ void k_fill(const int* __restrict__ src, const int* __restrict__ dst,
                       const float* __restrict__ ew, int* __restrict__ pos,
                       int4* __restrict__ csr, int E) {
    int e = blockIdx.x * 256 + threadIdx.x;
    if (e < E) {
        int d = dst[e];
        int slot = atomicAdd(&pos[d], 1);
        csr[slot] = make_int4(src[e], __float_as_int(ew[e]), d, 0);  // one 16B store
    }
}

// ---------------- weight pack (all 6 matrices, one launch) -----------------
__device__ __forceinline__ void pack_one(const float* __restrict__ w,
                                         unsigned short* __restrict__ hi,
                                         unsigned short* __restrict__ lo,
                                         int K, int Hc, int i) {
    int KF = K >> 5;
    int j    = i & 7;
    int lane = (i >> 3) & 63;
    int fb   = i >> 9;
    int kf   = fb % KF;
    int cg   = fb / KF;
    int k    = kf * 32 + ((lane >> 4) << 3) + j;
    int col  = cg * 16 + (lane & 15);
    float x = w[k * Hc + col];
    unsigned short h = f2bf_rne(x);
    hi[i] = h;
    lo[i] = f2bf_rne(x - bf2f(h));
}

__global__ void k_pack_all(const float* w11, const float* w12, const float* w21,
                           const float* w22, const float* w31, const float* w32,
                           unsigned short* p11h, unsigned short* p11l,
                           unsigned short* p12h, unsigned short* p12l,
                           unsigned short* p21h, unsigned short* p21l,
                           unsigned short* p22h, unsigned short* p22l,
                           unsigned short* p31h, unsigned short* p31l,
                           unsigned short* p32h, unsigned short* p32l) {
    int i = blockIdx.x * 256 + threadIdx.x;         // 0..32767
    if      (i <  4096) pack_one(w11, p11h, p11l,  64,  64, i);
    else if (i <  8192) pack_one(w12, p12h, p12l,  64,  64, i - 4096);
    else if (i < 16384) pack_one(w21, p21h, p21l,  64, 128, i - 8192);
    else if (i < 24576) pack_one(w22, p22h, p22l, 128,  64, i - 16384);
    else if (i < 28672) pack_one(w31, p31h, p31l,  64,  64, i - 24576);
    else                pack_one(w32, p32h, p32l,  64,  64, i - 28672);
}

// ---------------- fused layer: edge-parallel gather + bf16x3 MFMA MLP ------
// Block = 256 threads = 4 waves = 64 nodes (block-level LDS tile).
template<int H, bool RELU_OUT>
__global__ __launch_bounds__(256)
void k_layer(const float* __restrict__ in, float* __restrict__ out,
             const int* __restrict__ rowptr, const int4* __restrict__ csr,
             const unsigned short* __restrict__ w1h, const unsigned short* __restrict__ w1l,
             const float* __restrict__ b1,
             const unsigned short* __restrict__ w2h, const unsigned short* __restrict__ w2l,
             const float* __restrict__ b2, int N) {
    constexpr int SA  = 68;                      // A-tile stride (floats)
    constexpr int SH  = H + 4;                   // h-tile stride
    constexpr int NS  = 64 * (SH > SA ? SH : SA);
    constexpr int CG1 = H / 16;                  // phase-1 col groups
    constexpr int KF2 = H / 32;                  // phase-2 k frags
    __shared__ float S[NS];

    const int t    = threadIdx.x;
    const int wv   = t >> 6, lane = t & 63;
    const int g    = lane >> 4;      // lane group 0..3
    const int f    = lane & 15;      // feature quad
    const int node0 = blockIdx.x * 64;
    const float4* in4 = reinterpret_cast<const float4*>(in);

    // ---- stage 64 x-rows into A-tile (coalesced; fuses the "+x") ----
#pragma unroll
    for (int it = 0; it < 4; ++it) {
        int idx = it * 256 + t;                  // float4 slot 0..1023
        int n = idx >> 4, qq = idx & 15;
        float4 v = make_float4(0.f, 0.f, 0.f, 0.f);
        if (node0 + n < N)
            v = in4[(size_t)(node0 + n) * 16 + qq];
        *reinterpret_cast<float4*>(&S[n * SA + 4 * qq]) = v;
    }

    // block's contiguous edge range (CSR is dst-sorted)
    const int nend = (node0 + 64 < N) ? node0 + 64 : N;
    const int ebeg = rowptr[node0];
    const int eend = rowptr[nend];
    __syncthreads();

    // ---- flat edge loop: 16 groups x 2 edges/iter, ds_add_f32 into tile ----
    for (int eb = ebeg + (wv * 4 + g) * 2; eb < eend; eb += 32) {
        int4 e0 = csr[eb];
        int4 e1 = (eb + 1 < eend) ? csr[eb + 1]
                                  : make_int4(0, 0, node0, 0);   // w=0 pad
        float4 v0 = in4[(size_t)e0.x * 16 + f];
        float4 v1 = in4[(size_t)e1.x * 16 + f];
        float w0 = __int_as_float(e0.y);
        float w1 = __int_as_float(e1.y);
        float* p0 = &S[(e0.z - node0) * SA + 4 * f];
        float* p1 = &S[(e1.z - node0) * SA + 4 * f];
        atomicAdd(p0 + 0, w0 * v0.x); atomicAdd(p0 + 1, w0 * v0.y);
        atomicAdd(p0 + 2, w0 * v0.z); atomicAdd(p0 + 3, w0 * v0.w);
        atomicAdd(p1 + 0, w1 * v1.x); atomicAdd(p1 + 1, w1 * v1.y);
        atomicAdd(p1 + 2, w1 * v1.z); atomicAdd(p1 + 3, w1 * v1.w);
    }
    __syncthreads();

    // ---- A-frags (K=64 -> 2 kf) from block tile, split hi/lo ----
    const int m = f;                 // node within wave's 16
    const int q = g;                 // k-chunk
    bfrag ah[2], al[2];
#pragma unroll
    for (int kf = 0; kf < 2; ++kf) {
        const float* base = &S[(wv * 16 + m) * SA + kf * 32 + q * 8];
        float4 u0 = *reinterpret_cast<const float4*>(base);
        float4 u1 = *reinterpret_cast<const float4*>(base + 4);
        float u[8] = {u0.x, u0.y, u0.z, u0.w, u1.x, u1.y, u1.z, u1.w};
#pragma unroll
        for (int j = 0; j < 8; ++j) {
            unsigned short hb = f2bf_rne(u[j]);
            ah[kf][j] = (short)hb;
            al[kf][j] = (short)f2bf_rne(u[j] - bf2f(hb));
        }
    }
    __syncthreads();   // A-tile consumed by ALL waves -> safe to overlay h

    const bfrag* w1hp = reinterpret_cast<const bfrag*>(w1h);
    const bfrag* w1lp = reinterpret_cast<const bfrag*>(w1l);
    const bfrag* w2hp = reinterpret_cast<const bfrag*>(w2h);
    const bfrag* w2lp = reinterpret_cast<const bfrag*>(w2l);

    // ---- phase 1: h = relu(A@W1 + b1) -> LDS ----
#pragma unroll
    for (int cg = 0; cg < CG1; ++cg) {
        ffrag c = {0.f, 0.f, 0.f, 0.f};
#pragma unroll
        for (int kf = 0; kf < 2; ++kf) {
            bfrag bh = w1hp[(cg * 2 + kf) * 64 + lane];
            bfrag bl = w1lp[(cg * 2 + kf) * 64 + lane];
            c = __builtin_amdgcn_mfma_f32_16x16x32_bf16(ah[kf], bh, c, 0, 0, 0);
            c = __builtin_amdgcn_mfma_f32_16x16x32_bf16(al[kf], bh, c, 0, 0, 0);
            c = __builtin_amdgcn_mfma_f32_16x16x32_bf16(ah[kf], bl, c, 0, 0, 0);
        }
        float bias = b1[cg * 16 + m];
#pragma unroll
        for (int r = 0; r < 4; ++r) {
            float hv = fmaxf(c[r] + bias, 0.f);
            S[(wv * 16 + q * 4 + r) * SH + cg * 16 + m] = hv;  // row=node, col=h
        }
    }
    __syncthreads();

    // ---- h -> A frags (hi/lo) ----
    bfrag gh[KF2], gl[KF2];
#pragma unroll
    for (int kf = 0; kf < KF2; ++kf) {
        const float* base = &S[(wv * 16 + m) * SH + kf * 32 + q * 8];
        float4 u0 = *reinterpret_cast<const float4*>(base);
        float4 u1 = *reinterpret_cast<const float4*>(base + 4);
        float u[8] = {u0.x, u0.y, u0.z, u0.w, u1.x, u1.y, u1.z, u1.w};
#pragma unroll
        for (int j = 0; j < 8; ++j) {
            unsigned short hb = f2bf_rne(u[j]);
            gh[kf][j] = (short)hb;
            gl[kf][j] = (short)f2bf_rne(u[j] - bf2f(hb));
        }
    }

    // ---- phase 2: out = h@W2 + b2 ----
#pragma unroll
    for (int cg = 0; cg < 4; ++cg) {
        ffrag c = {0.f, 0.f, 0.f, 0.f};
#pragma unroll
        for (int kf = 0; kf < KF2; ++kf) {
            bfrag bh = w2hp[(cg * KF2 + kf) * 64 + lane];
            bfrag bl = w2lp[(cg * KF2 + kf) * 64 + lane];
            c = __builtin_amdgcn_mfma_f32_16x16x32_bf16(gh[kf], bh, c, 0, 0, 0);
            c = __builtin_amdgcn_mfma_f32_16x16x32_bf16(gl[kf], bh, c, 0, 0, 0);
            c = __builtin_amdgcn_mfma_f32_16x16x32_bf16(gh[kf], bl, c, 0, 0, 0);
        }
        float bias = b2[cg * 16 + m];
#pragma unroll
        for (int r = 0; r < 4; ++r) {
            int nd = node0 + wv * 16 + q * 4 + r;
            if (nd < N) {
                float v = c[r] + bias;
                if (RELU_OUT) v = fmaxf(v, 0.f);
                out[(size_t)nd * FEAT + cg * 16 + m] = v;
            }
        }
    }
}

// ---------------------------------------------------------------------------
extern "C" void kernel_launch(void* const* d_in, const int* in_sizes, int n_in,
                              void* d_out, int out_size, void* d_ws, size_t ws_size,
                              hipStream_t stream) {
    const float* x   = (const float*)d_in[0];
    const int*   ei  = (const int*)  d_in[1];
    const float* ew  = (const float*)d_in[2];
    const float* w11 = (const float*)d_in[3];
    const float* b11 = (const float*)d_in[4];
    const float* w12 = (const float*)d_in[5];
    const float* b12 = (const float*)d_in[6];
    const float* w21 = (const float*)d_in[7];
    const float* b21 = (const float*)d_in[8];
    const float* w22 = (const float*)d_in[9];
    const float* b22 = (const float*)d_in[10];
    const float* w31 = (const float*)d_in[11];
    const float* b31 = (const float*)d_in[12];
    const float* w32 = (const float*)d_in[13];
    const float* b32 = (const float*)d_in[14];

    const int N = in_sizes[0] / FEAT;   // 100000
    const int E = in_sizes[2];          // 1000000
    const int* srci = ei;
    const int* dsti = ei + E;

    // ---- workspace layout ----
    float* buf1   = (float*)d_ws;                       // [N*64] layer-1 out
    float* buf2   = buf1 + (size_t)N * FEAT;            // [N*64] layer-2 out
    int*   rowptr = (int*)(buf2 + (size_t)N * FEAT);    // [N+1]
    int*   pos    = rowptr + (N + 1);                   // [N]
    int*   deg    = pos + N;                            // [N]
    int*   bsums  = deg + N;                            // [512]
    size_t c16 = ((size_t)(bsums + 512) + 15) & ~(size_t)15;
    int4*  csr    = (int4*)c16;                         // [E] (src, w, dst, 0)
    size_t pk = (size_t)(csr + E);
    unsigned short* p11h = (unsigned short*)pk;         // 4096 each for 64x64
    unsigned short* p11l = p11h + 4096;
    unsigned short* p12h = p11l + 4096;
    unsigned short* p12l = p12h + 4096;
    unsigned short* p21h = p12l + 4096;                 // 8192 for 64x128
    unsigned short* p21l = p21h + 8192;
    unsigned short* p22h = p21l + 8192;                 // 8192 for 128x64
    unsigned short* p22l = p22h + 8192;
    unsigned short* p31h = p22l + 8192;
    unsigned short* p31l = p31h + 4096;
    unsigned short* p32h = p31l + 4096;
    unsigned short* p32l = p32h + 4096;
    float* outF   = (float*)d_out;                      // [N*64]

    const int gE   = (E + 255) / 256;
    const int gN   = (N + 255) / 256;
    const int nb1  = (N + 255) / 256;
    const int gN1  = (N + 1 + 255) / 256;
    const int gLay = (N + 63) / 64;

    // ---- CSR build ----
    k_zero <<<gN,  256, 0, stream>>>(deg, N);
    k_hist <<<gE,  256, 0, stream>>>(dsti, deg, E);
    k_scan1<<<nb1, 256, 0, stream>>>(deg, rowptr, bsums, N);
    k_scan2<<<1,   512, 0, stream>>>(bsums, nb1);
    k_add  <<<gN1, 256, 0, stream>>>(rowptr, pos, bsums, N, E);
    k_fill <<<gE,  256, 0, stream>>>(srci, dsti, ew, pos, csr, E);

    // ---- pack all weights (frag order, bf16 hi/lo), one launch ----
    k_pack_all<<<128, 256, 0, stream>>>(w11, w12, w21, w22, w31, w32,
                                        p11h, p11l, p12h, p12l, p21h, p21l,
                                        p22h, p22l, p31h, p31l, p32h, p32l);

    // ---- 3 fused layers: x -> buf1 -> buf2 -> d_out ----
    k_layer<64,  true ><<<gLay, 256, 0, stream>>>(x,    buf1, rowptr, csr,
                                                  p11h, p11l, b11, p12h, p12l, b12, N);
    k_layer<128, true ><<<gLay, 256, 0, stream>>>(buf1, buf2, rowptr, csr,
                                                  p21h, p21l, b21, p22h, p22l, b22, N);
    k_layer<64,  false><<<gLay, 256, 0, stream>>>(buf2, outF, rowptr, csr,
                                                  p31h, p31l, b31, p32h, p32l, b32, N);
}

// Round 8
// 554.903 us; speedup vs baseline: 2.4461x; 2.4461x over previous
//
#include <hip/hip_runtime.h>
#include <math.h>

// ---------------------------------------------------------------------------
// GIN, 3 layers, N=100000, E=1000000, D=64, fp32 in/out.
// Round 8: round-5 gather/MLP (best known) + binned 2-level CSR build:
//   bin = 128 consecutive dst nodes (782 bins).
//   k_binhist (LDS hist, 200K atomics) -> k_binscan -> k_binscatter
//   (hot-tail-line scatter, ~50KB active) -> k_binsort (per-bin LDS count/
//   scan -> rowptr + in-L2 coalesced CSR placement).
//   Eliminates k_hist/k_scan1/k_scan2/k_add/k_fill (~110us -> ~40us).
// ---------------------------------------------------------------------------

#define FEAT 64
#define BINW 128           // nodes per bin
#define BSH  7             // log2(BINW)

typedef __attribute__((ext_vector_type(8))) short bfrag;   // 8 bf16 (4 VGPRs)
typedef __attribute__((ext_vector_type(4))) float ffrag;   // 4 fp32 acc

__device__ __forceinline__ unsigned short f2bf_rne(float x) {
    union { float f; unsigned u; } v; v.f = x;
    unsigned r = (v.u + 0x7fffu + ((v.u >> 16) & 1u)) >> 16;
    return (unsigned short)r;
}
__device__ __forceinline__ float bf2f(unsigned short h) {
    union { unsigned u; float f; } v; v.u = ((unsigned)h) << 16;
    return v.f;
}

// ---------------- binned CSR build -----------------------------------------
__global__ void k_zero(int* p, int n) {
    int i = blockIdx.x * 256 + threadIdx.x;
    if (i < n) p[i] = 0;
}

// 256 blocks, grid-stride; LDS histogram of dst>>7.
__global__ __launch_bounds__(256)
void k_binhist(const int* __restrict__ dst, int* __restrict__ bincnt,
               int E, int NBINS) {
    __shared__ int h[1024];
    int tid = threadIdx.x;
    for (int i = tid; i < NBINS; i += 256) h[i] = 0;
    __syncthreads();
    for (int e = blockIdx.x * 256 + tid; e < E; e += gridDim.x * 256)
        atomicAdd(&h[dst[e] >> BSH], 1);
    __syncthreads();
    for (int i = tid; i < NBINS; i += 256) {
        int v = h[i];
        if (v) atomicAdd(&bincnt[i], v);
    }
}

// single block: exclusive scan of bin counts -> binstart, binpos cursors.
__global__ __launch_bounds__(1024)
void k_binscan(const int* __restrict__ bincnt, int* __restrict__ binstart,
               int* __restrict__ binpos, int* __restrict__ rowptr,
               int NBINS, int E, int N) {
    __shared__ int tmp[1024];
    int tid = threadIdx.x;
    int v = (tid < NBINS) ? bincnt[tid] : 0;
    tmp[tid] = v;
    __syncthreads();
    for (int off = 1; off < 1024; off <<= 1) {
        int t = (tid >= off) ? tmp[tid - off] : 0;
        __syncthreads();
        tmp[tid] += t;
        __syncthreads();
    }
    if (tid < NBINS) {
        int ex = tmp[tid] - v;
        binstart[tid] = ex;
        binpos[tid]   = ex;
    }
    if (tid == 0) { binstart[NBINS] = E; rowptr[N] = E; }
}

// per-edge scatter into bin-sorted buffer (only ~NBINS hot tail lines).
__global__ void k_binscatter(const int* __restrict__ src, const int* __restrict__ dst,
                             const float* __restrict__ ew, int* __restrict__ binpos,
                             int4* __restrict__ binbuf, int E) {
    int e = blockIdx.x * 256 + threadIdx.x;
    if (e < E) {
        int d = dst[e];
        int slot = atomicAdd(&binpos[d >> BSH], 1);
        binbuf[slot] = make_int4(src[e], __float_as_int(ew[e]), d, 0);
    }
}

// one block per bin: count 128 nodes -> scan -> rowptr -> place edges.
__global__ __launch_bounds__(256)
void k_binsort(const int4* __restrict__ binbuf, const int* __restrict__ binstart,
               int* __restrict__ rowptr, int2* __restrict__ csr, int N) {
    __shared__ int cnt[BINW];
    __shared__ int cur[BINW];
    const int b    = blockIdx.x;
    const int base = binstart[b];
    const int ne   = binstart[b + 1] - base;
    const int tid  = threadIdx.x;

    if (tid < BINW) cnt[tid] = 0;
    __syncthreads();
    for (int i = tid; i < ne; i += 256)
        atomicAdd(&cnt[binbuf[base + i].z & (BINW - 1)], 1);
    __syncthreads();
    if (tid < BINW) cur[tid] = cnt[tid];
    __syncthreads();
    for (int off = 1; off < BINW; off <<= 1) {
        int v = (tid < BINW && tid >= off) ? cur[tid - off] : 0;
        __syncthreads();
        if (tid < BINW) cur[tid] += v;
        __syncthreads();
    }
    if (tid < BINW) {
        int ex = cur[tid] - cnt[tid];          // exclusive within bin
        int node = b * BINW + tid;
        if (node < N) rowptr[node] = base + ex;
        cur[tid] = ex;                         // cursor
    }
    __syncthreads();
    for (int i = tid; i < ne; i += 256) {
        int4 e = binbuf[base + i];
        int r = atomicAdd(&cur[e.z & (BINW - 1)], 1);
        csr[base + r] = make_int2(e.x, e.y);   // in-L2, bin-local window
    }
}

// ---------------- weight pack (all 6 matrices, one launch) -----------------
__device__ __forceinline__ void pack_one(const float* __restrict__ w,
                                         unsigned short* __restrict__ hi,
                                         unsigned short* __restrict__ lo,
                                         int K, int Hc, int i) {
    int KF = K >> 5;
    int j    = i & 7;
    int lane = (i >> 3) & 63;
    int fb   = i >> 9;
    int kf   = fb % KF;
    int cg   = fb / KF;
    int k    = kf * 32 + ((lane >> 4) << 3) + j;
    int col  = cg * 16 + (lane & 15);
    float x = w[k * Hc + col];
    unsigned short h = f2bf_rne(x);
    hi[i] = h;
    lo[i] = f2bf_rne(x - bf2f(h));
}

__global__ void k_pack_all(const float* w11, const float* w12, const float* w21,
                           const float* w22, const float* w31, const float* w32,
                           unsigned short* p11h, unsigned short* p11l,
                           unsigned short* p12h, unsigned short* p12l,
                           unsigned short* p21h, unsigned short* p21l,
                           unsigned short* p22h, unsigned short* p22l,
                           unsigned short* p31h, unsigned short* p31l,
                           unsigned short* p32h, unsigned short* p32l) {
    int i = blockIdx.x * 256 + threadIdx.x;         // 0..32767
    if      (i <  4096) pack_one(w11, p11h, p11l,  64,  64, i);
    else if (i <  8192) pack_one(w12, p12h, p12l,  64,  64, i - 4096);
    else if (i < 16384) pack_one(w21, p21h, p21l,  64, 128, i - 8192);
    else if (i < 24576) pack_one(w22, p22h, p22l, 128,  64, i - 16384);
    else if (i < 28672) pack_one(w31, p31h, p31l,  64,  64, i - 24576);
    else                pack_one(w32, p32h, p32l,  64,  64, i - 28672);
}

// ---------------- gather: wave=node, 4 edge-slots x 16 float4-lanes --------
// 16 edges per iteration; avg degree 10 -> usually a single iteration.
__global__ __launch_bounds__(256)
void k_gather2(const float* __restrict__ in, float* __restrict__ agg,
               const int* __restrict__ rowptr, const int2* __restrict__ csr,
               int N) {
    int wid = (blockIdx.x * 256 + threadIdx.x) >> 6;
    int lane = threadIdx.x & 63;
    wid = __builtin_amdgcn_readfirstlane(wid);
    if (wid >= N) return;
    const int qw = lane >> 4;   // edge slot 0..3
    const int f  = lane & 15;   // feature quad
    const int beg = rowptr[wid];
    const int end = rowptr[wid + 1];
    const float4* in4 = reinterpret_cast<const float4*>(in);

    float4 xr = in4[(size_t)wid * 16 + f];   // "+x", independent: issue early

    float4 acc = make_float4(0.f, 0.f, 0.f, 0.f);
    for (int p = beg; p < end; p += 16) {
        int   s[4];
        float w[4];
#pragma unroll
        for (int u = 0; u < 4; ++u) {
            int i = p + 4 * u + qw;
            int2 ev = make_int2(0, 0);
            if (i < end) ev = csr[i];        // one dwordx2
            s[u] = ev.x;
            w[u] = __int_as_float(ev.y);     // 0.0f when inactive
        }
        float4 v[4];
#pragma unroll
        for (int u = 0; u < 4; ++u)
            v[u] = in4[(size_t)s[u] * 16 + f];   // 4 row-loads in flight
#pragma unroll
        for (int u = 0; u < 4; ++u) {
            acc.x = fmaf(w[u], v[u].x, acc.x);
            acc.y = fmaf(w[u], v[u].y, acc.y);
            acc.z = fmaf(w[u], v[u].z, acc.z);
            acc.w = fmaf(w[u], v[u].w, acc.w);
        }
    }
    // butterfly across the 4 edge-slots (lane bits 4,5)
    acc.x += __shfl_xor(acc.x, 16); acc.y += __shfl_xor(acc.y, 16);
    acc.z += __shfl_xor(acc.z, 16); acc.w += __shfl_xor(acc.w, 16);
    acc.x += __shfl_xor(acc.x, 32); acc.y += __shfl_xor(acc.y, 32);
    acc.z += __shfl_xor(acc.z, 32); acc.w += __shfl_xor(acc.w, 32);

    acc.x += xr.x; acc.y += xr.y; acc.z += xr.z; acc.w += xr.w;
    if (qw == 0)
        reinterpret_cast<float4*>(agg)[(size_t)wid * 16 + f] = acc;
}

// ---------------- MFMA MLP: out = relu?(relu(A@W1+b1)@W2+b2) ---------------
// Block 256 = 4 waves, 16 nodes/wave. bf16x3 split precision.
template<int H, bool RELU_OUT>
__global__ __launch_bounds__(256)
void k_mlp3(const float* __restrict__ in, float* __restrict__ out,
            const unsigned short* __restrict__ w1h, const unsigned short* __restrict__ w1l,
            const float* __restrict__ b1,
            const unsigned short* __restrict__ w2h, const unsigned short* __restrict__ w2l,
            const float* __restrict__ b2, int N) {
    constexpr int SH  = H + 4;      // LDS h-row stride: 2-way bank alias only
    constexpr int CG1 = H / 16;     // phase-1 col groups
    constexpr int KF2 = H / 32;     // phase-2 k frags
    __shared__ float hs[4 * 16 * SH];

    const int t = threadIdx.x;
    const int wv = t >> 6, lane = t & 63;
    const int m = lane & 15, q = lane >> 4;
    const int node0 = blockIdx.x * 64 + wv * 16;
    float* hw = &hs[wv * 16 * SH];

    const bfrag* w1hp = reinterpret_cast<const bfrag*>(w1h);
    const bfrag* w1lp = reinterpret_cast<const bfrag*>(w1l);
    const bfrag* w2hp = reinterpret_cast<const bfrag*>(w2h);
    const bfrag* w2lp = reinterpret_cast<const bfrag*>(w2l);

    // ---- load A frags (K=64 -> 2 kf), split hi/lo ----
    bfrag ah[2], al[2];
    const int nodeA = node0 + m;
#pragma unroll
    for (int kf = 0; kf < 2; ++kf) {
        float u[8] = {0.f, 0.f, 0.f, 0.f, 0.f, 0.f, 0.f, 0.f};
        if (nodeA < N) {
            const float* base = in + (size_t)nodeA * FEAT + kf * 32 + q * 8;
            float4 u0 = *reinterpret_cast<const float4*>(base);
            float4 u1 = *reinterpret_cast<const float4*>(base + 4);
            u[0] = u0.x; u[1] = u0.y; u[2] = u0.z; u[3] = u0.w;
            u[4] = u1.x; u[5] = u1.y; u[6] = u1.z; u[7] = u1.w;
        }
#pragma unroll
        for (int j = 0; j < 8; ++j) {
            unsigned short hb = f2bf_rne(u[j]);
            ah[kf][j] = (short)hb;
            al[kf][j] = (short)f2bf_rne(u[j] - bf2f(hb));
        }
    }

    // ---- phase 1: h = relu(A@W1 + b1) -> LDS (wave-private tile) ----
#pragma unroll
    for (int cg = 0; cg < CG1; ++cg) {
        ffrag c = {0.f, 0.f, 0.f, 0.f};
#pragma unroll
        for (int kf = 0; kf < 2; ++kf) {
            bfrag bh = w1hp[(cg * 2 + kf) * 64 + lane];
            bfrag bl = w1lp[(cg * 2 + kf) * 64 + lane];
            c = __builtin_amdgcn_mfma_f32_16x16x32_bf16(ah[kf], bh, c, 0, 0, 0);
            c = __builtin_amdgcn_mfma_f32_16x16x32_bf16(al[kf], bh, c, 0, 0, 0);
            c = __builtin_amdgcn_mfma_f32_16x16x32_bf16(ah[kf], bl, c, 0, 0, 0);
        }
        float bias = b1[cg * 16 + m];
#pragma unroll
        for (int r = 0; r < 4; ++r) {
            float hv = fmaxf(c[r] + bias, 0.f);
            hw[(q * 4 + r) * SH + cg * 16 + m] = hv;   // row=node, col=h-col
        }
    }
    __syncthreads();

    // ---- h -> A frags (hi/lo) ----
    bfrag gh[KF2], gl[KF2];
#pragma unroll
    for (int kf = 0; kf < KF2; ++kf) {
        const float* base = &hw[m * SH + kf * 32 + q * 8];
        float4 u0 = *reinterpret_cast<const float4*>(base);
        float4 u1 = *reinterpret_cast<const float4*>(base + 4);
        float u[8] = {u0.x, u0.y, u0.z, u0.w, u1.x, u1.y, u1.z, u1.w};
#pragma unroll
        for (int j = 0; j < 8; ++j) {
            unsigned short hb = f2bf_rne(u[j]);
            gh[kf][j] = (short)hb;
            gl[kf][j] = (short)f2bf_rne(u[j] - bf2f(hb));
        }
    }

    // ---- phase 2: out = h@W2 + b2 ----
#pragma unroll
    for (int cg = 0; cg < 4; ++cg) {
        ffrag c = {0.f, 0.f, 0.f, 0.f};
#pragma unroll
        for (int kf = 0; kf < KF2; ++kf) {
            bfrag bh = w2hp[(cg * KF2 + kf) * 64 + lane];
            bfrag bl = w2lp[(cg * KF2 + kf) * 64 + lane];
            c = __builtin_amdgcn_mfma_f32_16x16x32_bf16(gh[kf], bh, c, 0, 0, 0);
            c = __builtin_amdgcn_mfma_f32_16x16x32_bf16(gl[kf], bh, c, 0, 0, 0);
            c = __builtin_amdgcn_mfma_f32_16x16x32_bf16(gh[kf], bl, c, 0, 0, 0);
        }
        float bias = b2[cg * 16 + m];
#pragma unroll
        for (int r = 0; r < 4; ++r) {
            int nd = node0 + q * 4 + r;
            if (nd < N) {
                float v = c[r] + bias;
                if (RELU_OUT) v = fmaxf(v, 0.f);
                out[(size_t)nd * FEAT + cg * 16 + m] = v;
            }
        }
    }
}

// ---------------------------------------------------------------------------
extern "C" void kernel_launch(void* const* d_in, const int* in_sizes, int n_in,
                              void* d_out, int out_size, void* d_ws, size_t ws_size,
                              hipStream_t stream) {
    const float* x   = (const float*)d_in[0];
    const int*   ei  = (const int*)  d_in[1];
    const float* ew  = (const float*)d_in[2];
    const float* w11 = (const float*)d_in[3];
    const float* b11 = (const float*)d_in[4];
    const float* w12 = (const float*)d_in[5];
    const float* b12 = (const float*)d_in[6];
    const float* w21 = (const float*)d_in[7];
    const float* b21 = (const float*)d_in[8];
    const float* w22 = (const float*)d_in[9];
    const float* b22 = (const float*)d_in[10];
    const float* w31 = (const float*)d_in[11];
    const float* b31 = (const float*)d_in[12];
    const float* w32 = (const float*)d_in[13];
    const float* b32 = (const float*)d_in[14];

    const int N = in_sizes[0] / FEAT;   // 100000
    const int E = in_sizes[2];          // 1000000
    const int* srci = ei;
    const int* dsti = ei + E;
    const int NBINS = (N + BINW - 1) >> BSH;   // 782

    // ---- workspace layout ----
    float* agg      = (float*)d_ws;                     // [N*64]
    int*   rowptr   = (int*)(agg + (size_t)N * FEAT);   // [N+1]
    int*   bincnt   = rowptr + (N + 1);                 // [NBINS]
    int*   binstart = bincnt + NBINS;                   // [NBINS+1]
    int*   binpos   = binstart + NBINS + 1;             // [NBINS]
    size_t a16 = ((size_t)(binpos + NBINS) + 15) & ~(size_t)15;
    int4*  binbuf   = (int4*)a16;                       // [E] (src,w,dst,0)
    int2*  csr      = (int2*)(binbuf + E);              // [E] (src,w)
    size_t pk = (size_t)(csr + E);
    unsigned short* p11h = (unsigned short*)pk;         // 4096 each for 64x64
    unsigned short* p11l = p11h + 4096;
    unsigned short* p12h = p11l + 4096;
    unsigned short* p12l = p12h + 4096;
    unsigned short* p21h = p12l + 4096;                 // 8192 for 64x128
    unsigned short* p21l = p21h + 8192;
    unsigned short* p22h = p21l + 8192;                 // 8192 for 128x64
    unsigned short* p22l = p22h + 8192;
    unsigned short* p31h = p22l + 8192;
    unsigned short* p31l = p31h + 4096;
    unsigned short* p32h = p31l + 4096;
    unsigned short* p32l = p32h + 4096;
    float* outF   = (float*)d_out;                      // [N*64]

    const int gE   = (E + 255) / 256;
    const int gGat = (N * 64 + 255) / 256;              // wave per node
    const int gMlp = (N + 63) / 64;

    // ---- binned CSR build ----
    k_zero      <<<(NBINS + 255) / 256, 256, 0, stream>>>(bincnt, NBINS);
    k_binhist   <<<256,   256,  0, stream>>>(dsti, bincnt, E, NBINS);
    k_binscan   <<<1,     1024, 0, stream>>>(bincnt, binstart, binpos, rowptr,
                                             NBINS, E, N);
    k_binscatter<<<gE,    256,  0, stream>>>(srci, dsti, ew, binpos, binbuf, E);
    k_binsort   <<<NBINS, 256,  0, stream>>>(binbuf, binstart, rowptr, csr, N);

    // ---- pack all weights (frag order, bf16 hi/lo), one launch ----
    k_pack_all<<<128, 256, 0, stream>>>(w11, w12, w21, w22, w31, w32,
                                        p11h, p11l, p12h, p12l, p21h, p21l,
                                        p22h, p22l, p31h, p31l, p32h, p32l);

    // ---- layer 1 ----
    k_gather2<<<gGat, 256, 0, stream>>>(x, agg, rowptr, csr, N);
    k_mlp3<64,  true ><<<gMlp, 256, 0, stream>>>(agg, outF, p11h, p11l, b11, p12h, p12l, b12, N);
    // ---- layer 2 ----
    k_gather2<<<gGat, 256, 0, stream>>>(outF, agg, rowptr, csr, N);
    k_mlp3<128, true ><<<gMlp, 256, 0, stream>>>(agg, outF, p21h, p21l, b21, p22h, p22l, b22, N);
    // ---- layer 3 ----
    k_gather2<<<gGat, 256, 0, stream>>>(outF, agg, rowptr, csr, N);
    k_mlp3<64,  false><<<gMlp, 256, 0, stream>>>(agg, outF, p31h, p31l, b31, p32h, p32l, b32, N);
}

// Round 9
// 330.882 us; speedup vs baseline: 4.1022x; 1.6770x over previous
//
#include <hip/hip_runtime.h>
#include <math.h>

// ---------------------------------------------------------------------------
// GIN, 3 layers, N=100000, E=1000000, D=64, fp32 in/out.
// Round 9: atomic-free radix CSR build (lesson from R8: 1M global atomics on
// 782 counters serialize at ~185ns each -> 237us. Fix: per-(block,bin) counts
// + scans give every edge a deterministic slot; only LDS atomics remain).
//   k_cnt -> k_scanA -> k_scanB -> k_place -> k_binsort
// Gather (wave/node, 16 edges/iter) + bf16x3 MFMA MLP from round 5 (best).
// ---------------------------------------------------------------------------

#define FEAT  64
#define BINW  128          // nodes per bin
#define BSH   7            // log2(BINW)
#define NBLK  256          // edge-partition blocks

typedef __attribute__((ext_vector_type(8))) short bfrag;   // 8 bf16 (4 VGPRs)
typedef __attribute__((ext_vector_type(4))) float ffrag;   // 4 fp32 acc

__device__ __forceinline__ unsigned short f2bf_rne(float x) {
    union { float f; unsigned u; } v; v.f = x;
    unsigned r = (v.u + 0x7fffu + ((v.u >> 16) & 1u)) >> 16;
    return (unsigned short)r;
}
__device__ __forceinline__ float bf2f(unsigned short h) {
    union { unsigned u; float f; } v; v.u = ((unsigned)h) << 16;
    return v.f;
}

// ---------------- atomic-free radix CSR build ------------------------------
// counts layout: counts[bin * NBLK + block]

__global__ __launch_bounds__(256)
void k_cnt(const int* __restrict__ dst, int* __restrict__ counts,
           int E, int NBINS) {
    __shared__ int h[1024];
    const int b = blockIdx.x, tid = threadIdx.x;
    for (int i = tid; i < NBINS; i += 256) h[i] = 0;
    __syncthreads();
    const int chunk = (E + NBLK - 1) / NBLK;
    const int ebeg = b * chunk;
    const int eend = (ebeg + chunk < E) ? ebeg + chunk : E;
    for (int e = ebeg + tid; e < eend; e += 256)
        atomicAdd(&h[dst[e] >> BSH], 1);          // LDS atomic
    __syncthreads();
    for (int i = tid; i < NBINS; i += 256)
        counts[i * NBLK + b] = h[i];
}

// one block per bin: exclusive scan over the 256 block-counts (in place),
// emit bin total.
__global__ __launch_bounds__(256)
void k_scanA(int* __restrict__ counts, int* __restrict__ bintotal, int NBINS) {
    __shared__ int tmp[256];
    const int bin = blockIdx.x, tid = threadIdx.x;
    int c = counts[bin * NBLK + tid];
    tmp[tid] = c;
    __syncthreads();
    for (int off = 1; off < 256; off <<= 1) {
        int t = (tid >= off) ? tmp[tid - off] : 0;
        __syncthreads();
        tmp[tid] += t;
        __syncthreads();
    }
    counts[bin * NBLK + tid] = tmp[tid] - c;      // exclusive within bin
    if (tid == 255) bintotal[bin] = tmp[255];
}

// single block: exclusive scan of bin totals -> binstart.
__global__ __launch_bounds__(1024)
void k_scanB(const int* __restrict__ bintotal, int* __restrict__ binstart,
             int* __restrict__ rowptr, int NBINS, int E, int N) {
    __shared__ int tmp[1024];
    const int tid = threadIdx.x;
    int v = (tid < NBINS) ? bintotal[tid] : 0;
    tmp[tid] = v;
    __syncthreads();
    for (int off = 1; off < 1024; off <<= 1) {
        int t = (tid >= off) ? tmp[tid - off] : 0;
        __syncthreads();
        tmp[tid] += t;
        __syncthreads();
    }
    if (tid < NBINS) binstart[tid] = tmp[tid] - v;
    if (tid == 0) { binstart[NBINS] = E; rowptr[N] = E; }
}

// re-read chunk, place edges at binstart[bin]+offs[bin][b]+rank (LDS rank).
__global__ __launch_bounds__(256)
void k_place(const int* __restrict__ src, const int* __restrict__ dst,
             const float* __restrict__ ew, const int* __restrict__ counts,
             const int* __restrict__ binstart, int4* __restrict__ binbuf,
             int E, int NBINS) {
    __shared__ int base[1024];
    const int b = blockIdx.x, tid = threadIdx.x;
    for (int i = tid; i < NBINS; i += 256)
        base[i] = binstart[i] + counts[i * NBLK + b];
    __syncthreads();
    const int chunk = (E + NBLK - 1) / NBLK;
    const int ebeg = b * chunk;
    const int eend = (ebeg + chunk < E) ? ebeg + chunk : E;
    for (int e = ebeg + tid; e < eend; e += 256) {
        int d = dst[e];
        int slot = atomicAdd(&base[d >> BSH], 1);   // LDS atomic only
        binbuf[slot] = make_int4(src[e], __float_as_int(ew[e]), d, 0);
    }
}

// one block per bin: count 128 nodes -> scan -> rowptr -> place edges.
__global__ __launch_bounds__(256)
void k_binsort(const int4* __restrict__ binbuf, const int* __restrict__ binstart,
               int* __restrict__ rowptr, int2* __restrict__ csr, int N) {
    __shared__ int cnt[BINW];
    __shared__ int cur[BINW];
    const int b    = blockIdx.x;
    const int base = binstart[b];
    const int ne   = binstart[b + 1] - base;
    const int tid  = threadIdx.x;

    if (tid < BINW) cnt[tid] = 0;
    __syncthreads();
    for (int i = tid; i < ne; i += 256)
        atomicAdd(&cnt[binbuf[base + i].z & (BINW - 1)], 1);
    __syncthreads();
    if (tid < BINW) cur[tid] = cnt[tid];
    __syncthreads();
    for (int off = 1; off < BINW; off <<= 1) {
        int v = (tid < BINW && tid >= off) ? cur[tid - off] : 0;
        __syncthreads();
        if (tid < BINW) cur[tid] += v;
        __syncthreads();
    }
    if (tid < BINW) {
        int ex = cur[tid] - cnt[tid];          // exclusive within bin
        int node = b * BINW + tid;
        if (node < N) rowptr[node] = base + ex;
        cur[tid] = ex;                         // cursor
    }
    __syncthreads();
    for (int i = tid; i < ne; i += 256) {
        int4 e = binbuf[base + i];
        int r = atomicAdd(&cur[e.z & (BINW - 1)], 1);
        csr[base + r] = make_int2(e.x, e.y);   // bin-local window (L2-hot)
    }
}

// ---------------- weight pack (all 6 matrices, one launch) -----------------
__device__ __forceinline__ void pack_one(const float* __restrict__ w,
                                         unsigned short* __restrict__ hi,
                                         unsigned short* __restrict__ lo,
                                         int K, int Hc, int i) {
    int KF = K >> 5;
    int j    = i & 7;
    int lane = (i >> 3) & 63;
    int fb   = i >> 9;
    int kf   = fb % KF;
    int cg   = fb / KF;
    int k    = kf * 32 + ((lane >> 4) << 3) + j;
    int col  = cg * 16 + (lane & 15);
    float x = w[k * Hc + col];
    unsigned short h = f2bf_rne(x);
    hi[i] = h;
    lo[i] = f2bf_rne(x - bf2f(h));
}

__global__ void k_pack_all(const float* w11, const float* w12, const float* w21,
                           const float* w22, const float* w31, const float* w32,
                           unsigned short* p11h, unsigned short* p11l,
                           unsigned short* p12h, unsigned short* p12l,
                           unsigned short* p21h, unsigned short* p21l,
                           unsigned short* p22h, unsigned short* p22l,
                           unsigned short* p31h, unsigned short* p31l,
                           unsigned short* p32h, unsigned short* p32l) {
    int i = blockIdx.x * 256 + threadIdx.x;         // 0..32767
    if      (i <  4096) pack_one(w11, p11h, p11l,  64,  64, i);
    else if (i <  8192) pack_one(w12, p12h, p12l,  64,  64, i - 4096);
    else if (i < 16384) pack_one(w21, p21h, p21l,  64, 128, i - 8192);
    else if (i < 24576) pack_one(w22, p22h, p22l, 128,  64, i - 16384);
    else if (i < 28672) pack_one(w31, p31h, p31l,  64,  64, i - 24576);
    else                pack_one(w32, p32h, p32l,  64,  64, i - 28672);
}

// ---------------- gather: wave=node, 4 edge-slots x 16 float4-lanes --------
__global__ __launch_bounds__(256)
void k_gather2(const float* __restrict__ in, float* __restrict__ agg,
               const int* __restrict__ rowptr, const int2* __restrict__ csr,
               int N) {
    int wid = (blockIdx.x * 256 + threadIdx.x) >> 6;
    int lane = threadIdx.x & 63;
    wid = __builtin_amdgcn_readfirstlane(wid);
    if (wid >= N) return;
    const int qw = lane >> 4;   // edge slot 0..3
    const int f  = lane & 15;   // feature quad
    const int beg = rowptr[wid];
    const int end = rowptr[wid + 1];
    const float4* in4 = reinterpret_cast<const float4*>(in);

    float4 xr = in4[(size_t)wid * 16 + f];   // "+x", independent: issue early

    float4 acc = make_float4(0.f, 0.f, 0.f, 0.f);
    for (int p = beg; p < end; p += 16) {
        int   s[4];
        float w[4];
#pragma unroll
        for (int u = 0; u < 4; ++u) {
            int i = p + 4 * u + qw;
            int2 ev = make_int2(0, 0);
            if (i < end) ev = csr[i];        // one dwordx2
            s[u] = ev.x;
            w[u] = __int_as_float(ev.y);     // 0.0f when inactive
        }
        float4 v[4];
#pragma unroll
        for (int u = 0; u < 4; ++u)
            v[u] = in4[(size_t)s[u] * 16 + f];   // 4 row-loads in flight
#pragma unroll
        for (int u = 0; u < 4; ++u) {
            acc.x = fmaf(w[u], v[u].x, acc.x);
            acc.y = fmaf(w[u], v[u].y, acc.y);
            acc.z = fmaf(w[u], v[u].z, acc.z);
            acc.w = fmaf(w[u], v[u].w, acc.w);
        }
    }
    // butterfly across the 4 edge-slots (lane bits 4,5)
    acc.x += __shfl_xor(acc.x, 16); acc.y += __shfl_xor(acc.y, 16);
    acc.z += __shfl_xor(acc.z, 16); acc.w += __shfl_xor(acc.w, 16);
    acc.x += __shfl_xor(acc.x, 32); acc.y += __shfl_xor(acc.y, 32);
    acc.z += __shfl_xor(acc.z, 32); acc.w += __shfl_xor(acc.w, 32);

    acc.x += xr.x; acc.y += xr.y; acc.z += xr.z; acc.w += xr.w;
    if (qw == 0)
        reinterpret_cast<float4*>(agg)[(size_t)wid * 16 + f] = acc;
}

// ---------------- MFMA MLP: out = relu?(relu(A@W1+b1)@W2+b2) ---------------
template<int H, bool RELU_OUT>
__global__ __launch_bounds__(256)
void k_mlp3(const float* __restrict__ in, float* __restrict__ out,
            const unsigned short* __restrict__ w1h, const unsigned short* __restrict__ w1l,
            const float* __restrict__ b1,
            const unsigned short* __restrict__ w2h, const unsigned short* __restrict__ w2l,
            const float* __restrict__ b2, int N) {
    constexpr int SH  = H + 4;      // LDS h-row stride: 2-way bank alias only
    constexpr int CG1 = H / 16;     // phase-1 col groups
    constexpr int KF2 = H / 32;     // phase-2 k frags
    __shared__ float hs[4 * 16 * SH];

    const int t = threadIdx.x;
    const int wv = t >> 6, lane = t & 63;
    const int m = lane & 15, q = lane >> 4;
    const int node0 = blockIdx.x * 64 + wv * 16;
    float* hw = &hs[wv * 16 * SH];

    const bfrag* w1hp = reinterpret_cast<const bfrag*>(w1h);
    const bfrag* w1lp = reinterpret_cast<const bfrag*>(w1l);
    const bfrag* w2hp = reinterpret_cast<const bfrag*>(w2h);
    const bfrag* w2lp = reinterpret_cast<const bfrag*>(w2l);

    // ---- load A frags (K=64 -> 2 kf), split hi/lo ----
    bfrag ah[2], al[2];
    const int nodeA = node0 + m;
#pragma unroll
    for (int kf = 0; kf < 2; ++kf) {
        float u[8] = {0.f, 0.f, 0.f, 0.f, 0.f, 0.f, 0.f, 0.f};
        if (nodeA < N) {
            const float* base = in + (size_t)nodeA * FEAT + kf * 32 + q * 8;
            float4 u0 = *reinterpret_cast<const float4*>(base);
            float4 u1 = *reinterpret_cast<const float4*>(base + 4);
            u[0] = u0.x; u[1] = u0.y; u[2] = u0.z; u[3] = u0.w;
            u[4] = u1.x; u[5] = u1.y; u[6] = u1.z; u[7] = u1.w;
        }
#pragma unroll
        for (int j = 0; j < 8; ++j) {
            unsigned short hb = f2bf_rne(u[j]);
            ah[kf][j] = (short)hb;
            al[kf][j] = (short)f2bf_rne(u[j] - bf2f(hb));
        }
    }

    // ---- phase 1: h = relu(A@W1 + b1) -> LDS (wave-private tile) ----
#pragma unroll
    for (int cg = 0; cg < CG1; ++cg) {
        ffrag c = {0.f, 0.f, 0.f, 0.f};
#pragma unroll
        for (int kf = 0; kf < 2; ++kf) {
            bfrag bh = w1hp[(cg * 2 + kf) * 64 + lane];
            bfrag bl = w1lp[(cg * 2 + kf) * 64 + lane];
            c = __builtin_amdgcn_mfma_f32_16x16x32_bf16(ah[kf], bh, c, 0, 0, 0);
            c = __builtin_amdgcn_mfma_f32_16x16x32_bf16(al[kf], bh, c, 0, 0, 0);
            c = __builtin_amdgcn_mfma_f32_16x16x32_bf16(ah[kf], bl, c, 0, 0, 0);
        }
        float bias = b1[cg * 16 + m];
#pragma unroll
        for (int r = 0; r < 4; ++r) {
            float hv = fmaxf(c[r] + bias, 0.f);
            hw[(q * 4 + r) * SH + cg * 16 + m] = hv;   // row=node, col=h-col
        }
    }
    __syncthreads();

    // ---- h -> A frags (hi/lo) ----
    bfrag gh[KF2], gl[KF2];
#pragma unroll
    for (int kf = 0; kf < KF2; ++kf) {
        const float* base = &hw[m * SH + kf * 32 + q * 8];
        float4 u0 = *reinterpret_cast<const float4*>(base);
        float4 u1 = *reinterpret_cast<const float4*>(base + 4);
        float u[8] = {u0.x, u0.y, u0.z, u0.w, u1.x, u1.y, u1.z, u1.w};
#pragma unroll
        for (int j = 0; j < 8; ++j) {
            unsigned short hb = f2bf_rne(u[j]);
            gh[kf][j] = (short)hb;
            gl[kf][j] = (short)f2bf_rne(u[j] - bf2f(hb));
        }
    }

    // ---- phase 2: out = h@W2 + b2 ----
#pragma unroll
    for (int cg = 0; cg < 4; ++cg) {
        ffrag c = {0.f, 0.f, 0.f, 0.f};
#pragma unroll
        for (int kf = 0; kf < KF2; ++kf) {
            bfrag bh = w2hp[(cg * KF2 + kf) * 64 + lane];
            bfrag bl = w2lp[(cg * KF2 + kf) * 64 + lane];
            c = __builtin_amdgcn_mfma_f32_16x16x32_bf16(gh[kf], bh, c, 0, 0, 0);
            c = __builtin_amdgcn_mfma_f32_16x16x32_bf16(gl[kf], bh, c, 0, 0, 0);
            c = __builtin_amdgcn_mfma_f32_16x16x32_bf16(gh[kf], bl, c, 0, 0, 0);
        }
        float bias = b2[cg * 16 + m];
#pragma unroll
        for (int r = 0; r < 4; ++r) {
            int nd = node0 + q * 4 + r;
            if (nd < N) {
                float v = c[r] + bias;
                if (RELU_OUT) v = fmaxf(v, 0.f);
                out[(size_t)nd * FEAT + cg * 16 + m] = v;
            }
        }
    }
}

// ---------------------------------------------------------------------------
extern "C" void kernel_launch(void* const* d_in, const int* in_sizes, int n_in,
                              void* d_out, int out_size, void* d_ws, size_t ws_size,
                              hipStream_t stream) {
    const float* x   = (const float*)d_in[0];
    const int*   ei  = (const int*)  d_in[1];
    const float* ew  = (const float*)d_in[2];
    const float* w11 = (const float*)d_in[3];
    const float* b11 = (const float*)d_in[4];
    const float* w12 = (const float*)d_in[5];
    const float* b12 = (const float*)d_in[6];
    const float* w21 = (const float*)d_in[7];
    const float* b21 = (const float*)d_in[8];
    const float* w22 = (const float*)d_in[9];
    const float* b22 = (const float*)d_in[10];
    const float* w31 = (const float*)d_in[11];
    const float* b31 = (const float*)d_in[12];
    const float* w32 = (const float*)d_in[13];
    const float* b32 = (const float*)d_in[14];

    const int N = in_sizes[0] / FEAT;   // 100000
    const int E = in_sizes[2];          // 1000000
    const int* srci = ei;
    const int* dsti = ei + E;
    const int NBINS = (N + BINW - 1) >> BSH;   // 782

    // ---- workspace layout ----
    float* agg      = (float*)d_ws;                     // [N*64]
    int*   rowptr   = (int*)(agg + (size_t)N * FEAT);   // [N+1]
    int*   counts   = rowptr + (N + 1);                 // [NBINS*NBLK]
    int*   bintotal = counts + NBINS * NBLK;            // [NBINS]
    int*   binstart = bintotal + NBINS;                 // [NBINS+1]
    size_t a16 = ((size_t)(binstart + NBINS + 1) + 15) & ~(size_t)15;
    int4*  binbuf   = (int4*)a16;                       // [E] (src,w,dst,0)
    int2*  csr      = (int2*)(binbuf + E);              // [E] (src,w)
    size_t pk = (size_t)(csr + E);
    unsigned short* p11h = (unsigned short*)pk;         // 4096 each for 64x64
    unsigned short* p11l = p11h + 4096;
    unsigned short* p12h = p11l + 4096;
    unsigned short* p12l = p12h + 4096;
    unsigned short* p21h = p12l + 4096;                 // 8192 for 64x128
    unsigned short* p21l = p21h + 8192;
    unsigned short* p22h = p21l + 8192;                 // 8192 for 128x64
    unsigned short* p22l = p22h + 8192;
    unsigned short* p31h = p22l + 8192;
    unsigned short* p31l = p31h + 4096;
    unsigned short* p32h = p31l + 4096;
    unsigned short* p32l = p32h + 4096;
    float* outF   = (float*)d_out;                      // [N*64]

    const int gGat = (N * 64 + 255) / 256;              // wave per node
    const int gMlp = (N + 63) / 64;

    // ---- atomic-free radix CSR build ----
    k_cnt    <<<NBLK,  256,  0, stream>>>(dsti, counts, E, NBINS);
    k_scanA  <<<NBINS, 256,  0, stream>>>(counts, bintotal, NBINS);
    k_scanB  <<<1,     1024, 0, stream>>>(bintotal, binstart, rowptr, NBINS, E, N);
    k_place  <<<NBLK,  256,  0, stream>>>(srci, dsti, ew, counts, binstart,
                                          binbuf, E, NBINS);
    k_binsort<<<NBINS, 256,  0, stream>>>(binbuf, binstart, rowptr, csr, N);

    // ---- pack all weights (frag order, bf16 hi/lo), one launch ----
    k_pack_all<<<128, 256, 0, stream>>>(w11, w12, w21, w22, w31, w32,
                                        p11h, p11l, p12h, p12l, p21h, p21l,
                                        p22h, p22l, p31h, p31l, p32h, p32l);

    // ---- layer 1 ----
    k_gather2<<<gGat, 256, 0, stream>>>(x, agg, rowptr, csr, N);
    k_mlp3<64,  true ><<<gMlp, 256, 0, stream>>>(agg, outF, p11h, p11l, b11, p12h, p12l, b12, N);
    // ---- layer 2 ----
    k_gather2<<<gGat, 256, 0, stream>>>(outF, agg, rowptr, csr, N);
    k_mlp3<128, true ><<<gMlp, 256, 0, stream>>>(agg, outF, p21h, p21l, b21, p22h, p22l, b22, N);
    // ---- layer 3 ----
    k_gather2<<<gGat, 256, 0, stream>>>(outF, agg, rowptr, csr, N);
    k_mlp3<64,  false><<<gMlp, 256, 0, stream>>>(agg, outF, p31h, p31l, b31, p32h, p32l, b32, N);
}

// Round 10
// 312.616 us; speedup vs baseline: 4.3419x; 1.0584x over previous
//
#include <hip/hip_runtime.h>
#include <math.h>

// ---------------------------------------------------------------------------
// GIN, 3 layers, N=100000, E=1000000, D=64, fp32 in/out.
// Round 10: bf16 activation rows for the gather (halves the ~5x-amplified
// random row traffic: 256B -> 128B/row), fp32 accumulation + fp32 agg for the
// MLP (bf16x3 MFMA unchanged). Layer-1/2 MLP outputs stored bf16 (single
// reused buffer), layer-3 fp32 to d_out. binbuf packed to int2
// (key = dstlocal<<25 | src) halving k_place/k_binsort traffic.
// Atomic-free radix CSR build from round 9 otherwise unchanged.
// ---------------------------------------------------------------------------

#define FEAT  64
#define BINW  128          // nodes per bin
#define BSH   7            // log2(BINW)
#define NBLK  256          // edge-partition blocks
#define SRCB  25           // bits for src in packed key (N < 2^25)

typedef __attribute__((ext_vector_type(8))) short bfrag;   // 8 bf16 (4 VGPRs)
typedef __attribute__((ext_vector_type(4))) float ffrag;   // 4 fp32 acc

__device__ __forceinline__ unsigned short f2bf_rne(float x) {
    union { float f; unsigned u; } v; v.f = x;
    unsigned r = (v.u + 0x7fffu + ((v.u >> 16) & 1u)) >> 16;
    return (unsigned short)r;
}
__device__ __forceinline__ float bf2f(unsigned short h) {
    union { unsigned u; float f; } v; v.u = ((unsigned)h) << 16;
    return v.f;
}

// ---------------- x -> bf16 rows -------------------------------------------
__global__ void k_cvt(const float4* __restrict__ in, ushort4* __restrict__ out,
                      int n4) {
    int i = blockIdx.x * 256 + threadIdx.x;
    if (i < n4) {
        float4 v = in[i];
        ushort4 o;
        o.x = f2bf_rne(v.x); o.y = f2bf_rne(v.y);
        o.z = f2bf_rne(v.z); o.w = f2bf_rne(v.w);
        out[i] = o;
    }
}

// ---------------- atomic-free radix CSR build ------------------------------
// counts layout: counts[bin * NBLK + block]

__global__ __launch_bounds__(256)
void k_cnt(const int* __restrict__ dst, int* __restrict__ counts,
           int E, int NBINS) {
    __shared__ int h[1024];
    const int b = blockIdx.x, tid = threadIdx.x;
    for (int i = tid; i < NBINS; i += 256) h[i] = 0;
    __syncthreads();
    const int chunk = (E + NBLK - 1) / NBLK;
    const int ebeg = b * chunk;
    const int eend = (ebeg + chunk < E) ? ebeg + chunk : E;
    for (int e = ebeg + tid; e < eend; e += 256)
        atomicAdd(&h[dst[e] >> BSH], 1);          // LDS atomic
    __syncthreads();
    for (int i = tid; i < NBINS; i += 256)
        counts[i * NBLK + b] = h[i];
}

__global__ __launch_bounds__(256)
void k_scanA(int* __restrict__ counts, int* __restrict__ bintotal, int NBINS) {
    __shared__ int tmp[256];
    const int bin = blockIdx.x, tid = threadIdx.x;
    int c = counts[bin * NBLK + tid];
    tmp[tid] = c;
    __syncthreads();
    for (int off = 1; off < 256; off <<= 1) {
        int t = (tid >= off) ? tmp[tid - off] : 0;
        __syncthreads();
        tmp[tid] += t;
        __syncthreads();
    }
    counts[bin * NBLK + tid] = tmp[tid] - c;      // exclusive within bin
    if (tid == 255) bintotal[bin] = tmp[255];
}

__global__ __launch_bounds__(1024)
void k_scanB(const int* __restrict__ bintotal, int* __restrict__ binstart,
             int* __restrict__ rowptr, int NBINS, int E, int N) {
    __shared__ int tmp[1024];
    const int tid = threadIdx.x;
    int v = (tid < NBINS) ? bintotal[tid] : 0;
    tmp[tid] = v;
    __syncthreads();
    for (int off = 1; off < 1024; off <<= 1) {
        int t = (tid >= off) ? tmp[tid - off] : 0;
        __syncthreads();
        tmp[tid] += t;
        __syncthreads();
    }
    if (tid < NBINS) binstart[tid] = tmp[tid] - v;
    if (tid == 0) { binstart[NBINS] = E; rowptr[N] = E; }
}

// place edges at binstart[bin]+offs[bin][b]+rank; entry packed to int2.
__global__ __launch_bounds__(256)
void k_place(const int* __restrict__ src, const int* __restrict__ dst,
             const float* __restrict__ ew, const int* __restrict__ counts,
             const int* __restrict__ binstart, int2* __restrict__ binbuf,
             int E, int NBINS) {
    __shared__ int base[1024];
    const int b = blockIdx.x, tid = threadIdx.x;
    for (int i = tid; i < NBINS; i += 256)
        base[i] = binstart[i] + counts[i * NBLK + b];
    __syncthreads();
    const int chunk = (E + NBLK - 1) / NBLK;
    const int ebeg = b * chunk;
    const int eend = (ebeg + chunk < E) ? ebeg + chunk : E;
    for (int e = ebeg + tid; e < eend; e += 256) {
        int d = dst[e];
        int slot = atomicAdd(&base[d >> BSH], 1);   // LDS atomic only
        int key = ((d & (BINW - 1)) << SRCB) | src[e];
        binbuf[slot] = make_int2(key, __float_as_int(ew[e]));
    }
}

// one block per bin: count 128 nodes -> scan -> rowptr -> place edges.
__global__ __launch_bounds__(256)
void k_binsort(const int2* __restrict__ binbuf, const int* __restrict__ binstart,
               int* __restrict__ rowptr, int2* __restrict__ csr, int N) {
    __shared__ int cnt[BINW];
    __shared__ int cur[BINW];
    const int b    = blockIdx.x;
    const int base = binstart[b];
    const int ne   = binstart[b + 1] - base;
    const int tid  = threadIdx.x;

    if (tid < BINW) cnt[tid] = 0;
    __syncthreads();
    for (int i = tid; i < ne; i += 256)
        atomicAdd(&cnt[(binbuf[base + i].x >> SRCB) & (BINW - 1)], 1);
    __syncthreads();
    if (tid < BINW) cur[tid] = cnt[tid];
    __syncthreads();
    for (int off = 1; off < BINW; off <<= 1) {
        int v = (tid < BINW && tid >= off) ? cur[tid - off] : 0;
        __syncthreads();
        if (tid < BINW) cur[tid] += v;
        __syncthreads();
    }
    if (tid < BINW) {
        int ex = cur[tid] - cnt[tid];          // exclusive within bin
        int node = b * BINW + tid;
        if (node < N) rowptr[node] = base + ex;
        cur[tid] = ex;                         // cursor
    }
    __syncthreads();
    for (int i = tid; i < ne; i += 256) {
        int2 e = binbuf[base + i];
        int dl = (e.x >> SRCB) & (BINW - 1);
        int r = atomicAdd(&cur[dl], 1);
        csr[base + r] = make_int2(e.x & ((1 << SRCB) - 1), e.y);
    }
}

// ---------------- weight pack (all 6 matrices, one launch) -----------------
__device__ __forceinline__ void pack_one(const float* __restrict__ w,
                                         unsigned short* __restrict__ hi,
                                         unsigned short* __restrict__ lo,
                                         int K, int Hc, int i) {
    int KF = K >> 5;
    int j    = i & 7;
    int lane = (i >> 3) & 63;
    int fb   = i >> 9;
    int kf   = fb % KF;
    int cg   = fb / KF;
    int k    = kf * 32 + ((lane >> 4) << 3) + j;
    int col  = cg * 16 + (lane & 15);
    float x = w[k * Hc + col];
    unsigned short h = f2bf_rne(x);
    hi[i] = h;
    lo[i] = f2bf_rne(x - bf2f(h));
}

__global__ void k_pack_all(const float* w11, const float* w12, const float* w21,
                           const float* w22, const float* w31, const float* w32,
                           unsigned short* p11h, unsigned short* p11l,
                           unsigned short* p12h, unsigned short* p12l,
                           unsigned short* p21h, unsigned short* p21l,
                           unsigned short* p22h, unsigned short* p22l,
                           unsigned short* p31h, unsigned short* p31l,
                           unsigned short* p32h, unsigned short* p32l) {
    int i = blockIdx.x * 256 + threadIdx.x;         // 0..32767
    if      (i <  4096) pack_one(w11, p11h, p11l,  64,  64, i);
    else if (i <  8192) pack_one(w12, p12h, p12l,  64,  64, i - 4096);
    else if (i < 16384) pack_one(w21, p21h, p21l,  64, 128, i - 8192);
    else if (i < 24576) pack_one(w22, p22h, p22l, 128,  64, i - 16384);
    else if (i < 28672) pack_one(w31, p31h, p31l,  64,  64, i - 24576);
    else                pack_one(w32, p32h, p32l,  64,  64, i - 28672);
}

// ---------------- gather: bf16 rows in, fp32 agg out -----------------------
// wave=node, 4 edge-slots x 16 lanes (ushort4 = 4 features each), 16 edges/iter.
__global__ __launch_bounds__(256)
void k_gather3(const ushort* __restrict__ in, float* __restrict__ agg,
               const int* __restrict__ rowptr, const int2* __restrict__ csr,
               int N) {
    int wid = (blockIdx.x * 256 + threadIdx.x) >> 6;
    int lane = threadIdx.x & 63;
    wid = __builtin_amdgcn_readfirstlane(wid);
    if (wid >= N) return;
    const int qw = lane >> 4;   // edge slot 0..3
    const int f  = lane & 15;   // feature quad
    const int beg = rowptr[wid];
    const int end = rowptr[wid + 1];
    const ushort4* in4 = reinterpret_cast<const ushort4*>(in);

    ushort4 xr4 = in4[(size_t)wid * 16 + f];   // "+x", issue early

    float4 acc = make_float4(0.f, 0.f, 0.f, 0.f);
    for (int p = beg; p < end; p += 16) {
        int   s[4];
        float w[4];
#pragma unroll
        for (int u = 0; u < 4; ++u) {
            int i = p + 4 * u + qw;
            int2 ev = make_int2(0, 0);
            if (i < end) ev = csr[i];        // one dwordx2 (broadcast in group)
            s[u] = ev.x;
            w[u] = __int_as_float(ev.y);     // 0.0f when inactive
        }
        ushort4 v4[4];
#pragma unroll
        for (int u = 0; u < 4; ++u)
            v4[u] = in4[(size_t)s[u] * 16 + f];  // 4 row-loads in flight (128B/row)
#pragma unroll
        for (int u = 0; u < 4; ++u) {
            acc.x = fmaf(w[u], bf2f(v4[u].x), acc.x);
            acc.y = fmaf(w[u], bf2f(v4[u].y), acc.y);
            acc.z = fmaf(w[u], bf2f(v4[u].z), acc.z);
            acc.w = fmaf(w[u], bf2f(v4[u].w), acc.w);
        }
    }
    // butterfly across the 4 edge-slots (lane bits 4,5)
    acc.x += __shfl_xor(acc.x, 16); acc.y += __shfl_xor(acc.y, 16);
    acc.z += __shfl_xor(acc.z, 16); acc.w += __shfl_xor(acc.w, 16);
    acc.x += __shfl_xor(acc.x, 32); acc.y += __shfl_xor(acc.y, 32);
    acc.z += __shfl_xor(acc.z, 32); acc.w += __shfl_xor(acc.w, 32);

    acc.x += bf2f(xr4.x); acc.y += bf2f(xr4.y);
    acc.z += bf2f(xr4.z); acc.w += bf2f(xr4.w);
    if (qw == 0)
        reinterpret_cast<float4*>(agg)[(size_t)wid * 16 + f] = acc;
}

// ---------------- MFMA MLP: out = relu?(relu(A@W1+b1)@W2+b2) ---------------
// OUT_BF16: write bf16 activation rows (feeds next gather); else fp32.
template<int H, bool RELU_OUT, bool OUT_BF16>
__global__ __launch_bounds__(256)
void k_mlp3(const float* __restrict__ in, void* __restrict__ outv,
            const unsigned short* __restrict__ w1h, const unsigned short* __restrict__ w1l,
            const float* __restrict__ b1,
            const unsigned short* __restrict__ w2h, const unsigned short* __restrict__ w2l,
            const float* __restrict__ b2, int N) {
    constexpr int SH  = H + 4;      // LDS h-row stride: 2-way bank alias only
    constexpr int CG1 = H / 16;     // phase-1 col groups
    constexpr int KF2 = H / 32;     // phase-2 k frags
    __shared__ float hs[4 * 16 * SH];

    const int t = threadIdx.x;
    const int wv = t >> 6, lane = t & 63;
    const int m = lane & 15, q = lane >> 4;
    const int node0 = blockIdx.x * 64 + wv * 16;
    float* hw = &hs[wv * 16 * SH];

    const bfrag* w1hp = reinterpret_cast<const bfrag*>(w1h);
    const bfrag* w1lp = reinterpret_cast<const bfrag*>(w1l);
    const bfrag* w2hp = reinterpret_cast<const bfrag*>(w2h);
    const bfrag* w2lp = reinterpret_cast<const bfrag*>(w2l);

    // ---- load A frags (K=64 -> 2 kf), split hi/lo ----
    bfrag ah[2], al[2];
    const int nodeA = node0 + m;
#pragma unroll
    for (int kf = 0; kf < 2; ++kf) {
        float u[8] = {0.f, 0.f, 0.f, 0.f, 0.f, 0.f, 0.f, 0.f};
        if (nodeA < N) {
            const float* base = in + (size_t)nodeA * FEAT + kf * 32 + q * 8;
            float4 u0 = *reinterpret_cast<const float4*>(base);
            float4 u1 = *reinterpret_cast<const float4*>(base + 4);
            u[0] = u0.x; u[1] = u0.y; u[2] = u0.z; u[3] = u0.w;
            u[4] = u1.x; u[5] = u1.y; u[6] = u1.z; u[7] = u1.w;
        }
#pragma unroll
        for (int j = 0; j < 8; ++j) {
            unsigned short hb = f2bf_rne(u[j]);
            ah[kf][j] = (short)hb;
            al[kf][j] = (short)f2bf_rne(u[j] - bf2f(hb));
        }
    }

    // ---- phase 1: h = relu(A@W1 + b1) -> LDS (wave-private tile) ----
#pragma unroll
    for (int cg = 0; cg < CG1; ++cg) {
        ffrag c = {0.f, 0.f, 0.f, 0.f};
#pragma unroll
        for (int kf = 0; kf < 2; ++kf) {
            bfrag bh = w1hp[(cg * 2 + kf) * 64 + lane];
            bfrag bl = w1lp[(cg * 2 + kf) * 64 + lane];
            c = __builtin_amdgcn_mfma_f32_16x16x32_bf16(ah[kf], bh, c, 0, 0, 0);
            c = __builtin_amdgcn_mfma_f32_16x16x32_bf16(al[kf], bh, c, 0, 0, 0);
            c = __builtin_amdgcn_mfma_f32_16x16x32_bf16(ah[kf], bl, c, 0, 0, 0);
        }
        float bias = b1[cg * 16 + m];
#pragma unroll
        for (int r = 0; r < 4; ++r) {
            float hv = fmaxf(c[r] + bias, 0.f);
            hw[(q * 4 + r) * SH + cg * 16 + m] = hv;   // row=node, col=h-col
        }
    }
    __syncthreads();

    // ---- h -> A frags (hi/lo) ----
    bfrag gh[KF2], gl[KF2];
#pragma unroll
    for (int kf = 0; kf < KF2; ++kf) {
        const float* base = &hw[m * SH + kf * 32 + q * 8];
        float4 u0 = *reinterpret_cast<const float4*>(base);
        float4 u1 = *reinterpret_cast<const float4*>(base + 4);
        float u[8] = {u0.x, u0.y, u0.z, u0.w, u1.x, u1.y, u1.z, u1.w};
#pragma unroll
        for (int j = 0; j < 8; ++j) {
            unsigned short hb = f2bf_rne(u[j]);
            gh[kf][j] = (short)hb;
            gl[kf][j] = (short)f2bf_rne(u[j] - bf2f(hb));
        }
    }

    // ---- phase 2: out = h@W2 + b2 ----
#pragma unroll
    for (int cg = 0; cg < 4; ++cg) {
        ffrag c = {0.f, 0.f, 0.f, 0.f};
#pragma unroll
        for (int kf = 0; kf < KF2; ++kf) {
            bfrag bh = w2hp[(cg * KF2 + kf) * 64 + lane];
            bfrag bl = w2lp[(cg * KF2 + kf) * 64 + lane];
            c = __builtin_amdgcn_mfma_f32_16x16x32_bf16(gh[kf], bh, c, 0, 0, 0);
            c = __builtin_amdgcn_mfma_f32_16x16x32_bf16(gl[kf], bh, c, 0, 0, 0);
            c = __builtin_amdgcn_mfma_f32_16x16x32_bf16(gh[kf], bl, c, 0, 0, 0);
        }
        float bias = b2[cg * 16 + m];
#pragma unroll
        for (int r = 0; r < 4; ++r) {
            int nd = node0 + q * 4 + r;
            if (nd < N) {
                float v = c[r] + bias;
                if (RELU_OUT) v = fmaxf(v, 0.f);
                if (OUT_BF16)
                    ((unsigned short*)outv)[(size_t)nd * FEAT + cg * 16 + m] = f2bf_rne(v);
                else
                    ((float*)outv)[(size_t)nd * FEAT + cg * 16 + m] = v;
            }
        }
    }
}

// ---------------------------------------------------------------------------
extern "C" void kernel_launch(void* const* d_in, const int* in_sizes, int n_in,
                              void* d_out, int out_size, void* d_ws, size_t ws_size,
                              hipStream_t stream) {
    const float* x   = (const float*)d_in[0];
    const int*   ei  = (const int*)  d_in[1];
    const float* ew  = (const float*)d_in[2];
    const float* w11 = (const float*)d_in[3];
    const float* b11 = (const float*)d_in[4];
    const float* w12 = (const float*)d_in[5];
    const float* b12 = (const float*)d_in[6];
    const float* w21 = (const float*)d_in[7];
    const float* b21 = (const float*)d_in[8];
    const float* w22 = (const float*)d_in[9];
    const float* b22 = (const float*)d_in[10];
    const float* w31 = (const float*)d_in[11];
    const float* b31 = (const float*)d_in[12];
    const float* w32 = (const float*)d_in[13];
    const float* b32 = (const float*)d_in[14];

    const int N = in_sizes[0] / FEAT;   // 100000
    const int E = in_sizes[2];          // 1000000
    const int* srci = ei;
    const int* dsti = ei + E;
    const int NBINS = (N + BINW - 1) >> BSH;   // 782

    // ---- workspace layout ----
    float* agg      = (float*)d_ws;                     // [N*64] fp32
    unsigned short* xb = (unsigned short*)(agg + (size_t)N * FEAT); // [N*64] bf16
    int*   rowptr   = (int*)(xb + (size_t)N * FEAT);    // [N+1]
    int*   counts   = rowptr + (N + 1);                 // [NBINS*NBLK]
    int*   bintotal = counts + NBINS * NBLK;            // [NBINS]
    int*   binstart = bintotal + NBINS;                 // [NBINS+1]
    size_t a16 = ((size_t)(binstart + NBINS + 1) + 15) & ~(size_t)15;
    int2*  binbuf   = (int2*)a16;                       // [E] (key, w)
    int2*  csr      = (int2*)(binbuf + E);              // [E] (src, w)
    size_t pk = (size_t)(csr + E);
    unsigned short* p11h = (unsigned short*)pk;         // 4096 each for 64x64
    unsigned short* p11l = p11h + 4096;
    unsigned short* p12h = p11l + 4096;
    unsigned short* p12l = p12h + 4096;
    unsigned short* p21h = p12l + 4096;                 // 8192 for 64x128
    unsigned short* p21l = p21h + 8192;
    unsigned short* p22h = p21l + 8192;                 // 8192 for 128x64
    unsigned short* p22l = p22h + 8192;
    unsigned short* p31h = p22l + 8192;
    unsigned short* p31l = p31h + 4096;
    unsigned short* p32h = p31l + 4096;
    unsigned short* p32l = p32h + 4096;
    float* outF   = (float*)d_out;                      // [N*64]

    const int n4   = N * 16;
    const int gCvt = (n4 + 255) / 256;
    const int gGat = (N * 64 + 255) / 256;              // wave per node
    const int gMlp = (N + 63) / 64;

    // ---- x -> bf16 rows ----
    k_cvt<<<gCvt, 256, 0, stream>>>((const float4*)x, (ushort4*)xb, n4);

    // ---- atomic-free radix CSR build ----
    k_cnt    <<<NBLK,  256,  0, stream>>>(dsti, counts, E, NBINS);
    k_scanA  <<<NBINS, 256,  0, stream>>>(counts, bintotal, NBINS);
    k_scanB  <<<1,     1024, 0, stream>>>(bintotal, binstart, rowptr, NBINS, E, N);
    k_place  <<<NBLK,  256,  0, stream>>>(srci, dsti, ew, counts, binstart,
                                          binbuf, E, NBINS);
    k_binsort<<<NBINS, 256,  0, stream>>>(binbuf, binstart, rowptr, csr, N);

    // ---- pack all weights (frag order, bf16 hi/lo), one launch ----
    k_pack_all<<<128, 256, 0, stream>>>(w11, w12, w21, w22, w31, w32,
                                        p11h, p11l, p12h, p12l, p21h, p21l,
                                        p22h, p22l, p31h, p31l, p32h, p32l);

    // ---- layer 1: xb -> agg -> xb (bf16) ----
    k_gather3<<<gGat, 256, 0, stream>>>(xb, agg, rowptr, csr, N);
    k_mlp3<64,  true,  true ><<<gMlp, 256, 0, stream>>>(agg, xb, p11h, p11l, b11, p12h, p12l, b12, N);
    // ---- layer 2: xb -> agg -> xb (bf16) ----
    k_gather3<<<gGat, 256, 0, stream>>>(xb, agg, rowptr, csr, N);
    k_mlp3<128, true,  true ><<<gMlp, 256, 0, stream>>>(agg, xb, p21h, p21l, b21, p22h, p22l, b22, N);
    // ---- layer 3: xb -> agg -> d_out (fp32) ----
    k_gather3<<<gGat, 256, 0, stream>>>(xb, agg, rowptr, csr, N);
    k_mlp3<64,  false, false><<<gMlp, 256, 0, stream>>>(agg, outF, p31h, p31l, b31, p32h, p32l, b32, N);
}